// Round 10
// baseline (99.478 us; speedup 1.0000x reference)
//
#include <hip/hip_runtime.h>

// EdgeEmbedding: B=8, L=256, A=15, K=9, EDGE_SIZE=16 — single fused kernel.
//
// Output layout (all float32, concatenated flat):
//   [0,      30720)  block_id   = i/15
//   [30720,  32768)  batch_id   = i/256
//   [32768, 106496)  edges [2][36864]   (row0 src, row1 dst; intra then inter)
//   [106496,696320)  edge_attr [36864][16]
//
// Round-10 (round-9 post-mortem: selection tail was LDS pointer-chase bound,
// ~5k stall-cycles/wave; f64 refine ran even when f32 ordering was decisive):
//   1. f32 min-d^2/candidate: {-2x,-2y,-2z,x2} SGPR-pinned row atoms,
//      4 VALU/pair (3 fma + fmin), +c2 hoisted.
//   2. Histogram quantile (512 bins on bits>>19); ALL waves scan both classes
//      redundantly -> thresholds in registers (no sT barrier).
//   3. Mark d32 <= T + DELTA (DELTA=5e-3 >= 8x the 3e-4 f32 error bound =>
//      marked is a superset of the f64 top-9). Mark-time stores DENSE
//      (cand,cls) + key sVal[slot]=(double)d32 — later loops read
//      independent sequential addresses (no dependent LDS chains).
//   4. LAZY f64 refine: slot t needs refine iff some same-class slot is
//      within EPS2=2e-3 (>3x err). Typically zero -> refine loop skipped.
//      Refined slots get the full 225-pair f64 min (bit-identical to the
//      round-4 all-f64 kernel, which matched the oracle).
//      Mixed-key rank exactness: non-refined pairs separated >EPS2>2*err;
//      refined-vs-non separated >EPS2-2*err>err; refined-vs-refined true
//      f64 => every pairwise comparison equals the f64 ordering.
//   5. Rank per slot (independent broadcast LDS reads) -> top-9 winners
//      write their ordered edge slots directly.

#define BB   8
#define LL   256
#define AA   15
#define KK   9

#define O_BATCH   30720
#define O_EDGES   32768
#define NE_HALF   18432   // B*L*K
#define NE        36864
#define O_ATTR    106496
#define DELTA     0.005f
#define EPS2      2e-3
#define HBASE     1904    // (0x3B800000 >> 19): bins start at 2^-8
#define NBIN      512
#define MAXM      128     // marked-list capacity (observed cnt ~18-22)

__device__ __forceinline__ float rfl(float v) {
    return __int_as_float(__builtin_amdgcn_readfirstlane(__float_as_int(v)));
}

__global__ __launch_bounds__(256) void edge_fused_kernel(
    const float* __restrict__ pos,   // [B,L,A,3] f32
    const int*   __restrict__ frag,  // [B,L]
    const float* __restrict__ emb,   // [2,16]
    float*       __restrict__ out)
{
    const int blk = blockIdx.x;      // = b*256 + i
    const int b   = blk >> 8;
    const int i   = blk & 255;
    const int j   = threadIdx.x;     // candidate dst block

    __shared__ float4 sAi4[AA];      // row-i: {-2x, -2y, -2z, |x|^2}
    __shared__ double dAi[AA * 3];   // row-i coords (f64, rare-refine path)
    __shared__ double dX2i[AA];      // row-i |x|^2 (f64)
    __shared__ int    sHist[2*NBIN]; // per-class histogram
    __shared__ int    sList[MAXM];   // (cand<<1)|class, dense
    __shared__ double sVal[MAXM];    // comparison key (d32-promoted or d64)
    __shared__ int    sRList[MAXM];  // slots needing f64 refine
    __shared__ int    sCnt, sRCnt;

    // ---- fused trivial fills ----
    if (j < AA)  out[blk * AA + j]  = (float)blk;     // block_id
    if (j == AA) out[O_BATCH + blk] = (float)b;       // batch_id
    {
        int idx = blk * 288 + j;                      // 288 attr elems/block
        out[O_ATTR + idx] = emb[(((idx >> 4) < NE_HALF) ? 0 : 16) + (idx & 15)];
        if (j < 32) {
            int idx2 = idx + 256;
            out[O_ATTR + idx2] = emb[(((idx2 >> 4) < NE_HALF) ? 0 : 16) + (idx2 & 15)];
        }
    }

    // ---- stage row-i atoms; zero hist; init counters ----
    if (j < AA) {
        const float* p = pos + (size_t)blk * 45 + j * 3;
        float x = p[0], y = p[1], z = p[2];
        sAi4[j] = make_float4(-2.0f * x, -2.0f * y, -2.0f * z,
                              x*x + y*y + z*z);
        double dx = (double)x, dy = (double)y, dz = (double)z;
        dAi[3*j] = dx; dAi[3*j+1] = dy; dAi[3*j+2] = dz;
        dX2i[j] = dx*dx + dy*dy + dz*dz;
    }
    #pragma unroll
    for (int q = 0; q < 4; ++q) sHist[j + (q << 8)] = 0;   // 1024 ints
    if (j == 255) sCnt = 0;
    if (j == 254) sRCnt = 0;

    const int ftj  = frag[b * LL + j];
    const int segj = (ftj == 2) ? 1 : ftj;
    const int fti  = frag[blk];                       // uniform
    const int segi = (fti == 2) ? 1 : fti;
    // class: 0 = intra (seg==segi, j!=i), 1 = inter, -1 = self
    const int cls  = (j == i) ? -1 : ((segj == segi) ? 0 : 1);
    __syncthreads();                                  // bar 1

    // ---- row-i atoms: LDS once -> wave-uniform (SGPR) copies ----
    float Ax[AA], Ay[AA], Az[AA], Aw[AA];
    #pragma unroll
    for (int a = 0; a < AA; ++a) {
        float4 A = sAi4[a];
        Ax[a] = rfl(A.x); Ay[a] = rfl(A.y);
        Az[a] = rfl(A.z); Aw[a] = rfl(A.w);
    }

    // ---- phase 1: f32 min d^2, 3 chunks of 5 candidate atoms ----
    const float* pj = pos + (size_t)(b * LL + j) * 45;
    float d32 = INFINITY;
    #pragma unroll 1
    for (int cb = 0; cb < AA; cb += 5) {
        float cx[5], cy[5], cz[5], c2[5], m[5];
        #pragma unroll
        for (int q = 0; q < 5; ++q) {
            cx[q] = pj[3*(cb+q) + 0];
            cy[q] = pj[3*(cb+q) + 1];
            cz[q] = pj[3*(cb+q) + 2];
            c2[q] = cx[q]*cx[q] + cy[q]*cy[q] + cz[q]*cz[q];
            m[q]  = INFINITY;
        }
        #pragma unroll
        for (int a = 0; a < AA; ++a) {
            #pragma unroll
            for (int q = 0; q < 5; ++q) {
                float dp = fmaf(Ax[a], cx[q], fmaf(Ay[a], cy[q],
                            fmaf(Az[a], cz[q], Aw[a])));
                m[q] = fminf(m[q], dp);
            }
        }
        #pragma unroll
        for (int q = 0; q < 5; ++q)
            d32 = fminf(d32, m[q] + c2[q]);
    }
    d32 = fmaxf(d32, 0.0f);

    // ---- phase 2a: histogram (bits>>19 monotone for d32 >= 0) ----
    if (cls >= 0) {
        int bin = (int)(__float_as_uint(d32) >> 19) - HBASE;
        bin = min(NBIN - 1, max(0, bin));
        atomicAdd(&sHist[cls * NBIN + bin], 1);
    }
    __syncthreads();                                  // bar 2

    // ---- phase 2b: every wave scans BOTH classes (thresholds in regs) ----
    const int lane = j & 63;
    float T[2];
    #pragma unroll
    for (int cw = 0; cw < 2; ++cw) {
        int c[8], s = 0;
        #pragma unroll
        for (int q = 0; q < 8; ++q) {
            c[q] = sHist[cw * NBIN + 8*lane + q];
            s += c[q];
        }
        int cum = s;
        #pragma unroll
        for (int off = 1; off < 64; off <<= 1) {
            int v = __shfl_up(cum, off, 64);
            if (lane >= off) cum += v;
        }
        unsigned long long msk = __ballot(cum >= KK);
        float t_ = INFINITY;
        if (msk != 0ull) {
            int f = __builtin_ctzll(msk);
            if (lane == f) {
                int before = cum - s, bin = -1;
                #pragma unroll
                for (int q = 0; q < 8; ++q) {
                    before += c[q];
                    if (bin < 0 && before >= KK) bin = 8*f + q;
                }
                t_ = (bin >= NBIN - 1) ? INFINITY
                   : __uint_as_float((unsigned)(HBASE + bin + 1) << 19);
            }
            t_ = __shfl(t_, f, 64);                  // broadcast from lane f
        }
        T[cw] = t_;
    }

    // ---- phase 3: mark; store dense (cand,cls) + promoted-f32 key ----
    if (cls >= 0 && d32 <= T[cls] + DELTA) {
        int p = atomicAdd(&sCnt, 1);
        if (p < MAXM) {
            sList[p] = (j << 1) | cls;
            sVal[p]  = (double)d32;
        }
    }
    __syncthreads();                                  // bar 3
    const int cnt = min(sCnt, MAXM);                  // ~18-22

    // ---- phase 4a: near-tie detection (independent broadcast reads) ----
    if (j < cnt) {
        double my = sVal[j];
        int mycls = sList[j] & 1;
        bool need = false;
        for (int u = 0; u < cnt; ++u) {
            if (u != j && (sList[u] & 1) == mycls &&
                fabs(sVal[u] - my) <= EPS2) need = true;
        }
        if (need) { int p = atomicAdd(&sRCnt, 1); sRList[p] = j; }
    }
    __syncthreads();                                  // bar 4

    // ---- phase 4b: rare cooperative f64 refine (usually rcnt == 0) ----
    {
        const int rcnt = sRCnt;
        const int wv = j >> 6;
        for (int base = 0; base < rcnt; base += 4) {
            int t = base + wv;
            double dmin = INFINITY;
            int slot = -1;
            if (t < rcnt) {
                slot = sRList[t];
                int cand = sList[slot] >> 1;
                const float* pc = pos + (size_t)(b * LL + cand) * 45;
                for (int p = lane; p < 225; p += 64) {
                    int a = p / 15, c = p - a * 15;
                    double cx = (double)pc[3*c], cy = (double)pc[3*c+1],
                           cz = (double)pc[3*c+2];
                    double dot = dAi[3*a]*cx + dAi[3*a+1]*cy + dAi[3*a+2]*cz;
                    double d2  = (dX2i[a] + (cx*cx + cy*cy + cz*cz))
                               - 2.0 * dot;
                    dmin = fmin(dmin, d2);
                }
            }
            #pragma unroll
            for (int off = 1; off < 64; off <<= 1)
                dmin = fmin(dmin, __shfl_xor(dmin, off, 64));
            if (lane == 0 && t < rcnt) sVal[slot] = fmax(dmin, 0.0);
        }
    }
    __syncthreads();                                  // bar 5

    // ---- phase 5: rank per slot; winners write ordered edge slots ----
    if (j < cnt) {
        int e   = sList[j];
        int cnd = e >> 1, mycls = e & 1;
        double key = sVal[j];
        int r = 0;
        for (int u = 0; u < cnt; ++u) {
            int eu = sList[u];
            if ((eu & 1) == mycls) {
                double ku = sVal[u];
                int cu = eu >> 1;
                if (ku < key || (ku == key && cu < cnd)) ++r;
            }
        }
        r -= (mycls == 0 && r > 0 && false) ? 0 : 0;  // (self-count: u==j gives ku==key,cu==cnd -> not counted)
        if (r < KK) {
            int eo = (mycls == 0 ? 0 : NE_HALF) + blk * KK + r;
            out[O_EDGES + eo]      = (float)blk;            // src
            out[O_EDGES + NE + eo] = (float)(b * LL + cnd); // dst
        }
    }
}

extern "C" void kernel_launch(void* const* d_in, const int* in_sizes, int n_in,
                              void* d_out, int out_size, void* d_ws, size_t ws_size,
                              hipStream_t stream) {
    const float* pos  = (const float*)d_in[0];   // pos_heavyatom [8,256,15,3] f32
    const int*   frag = (const int*)d_in[6];     // fragment_type [8,256] i32
    const float* emb  = (const float*)d_in[7];   // edge_emb [2,16] f32
    float* out = (float*)d_out;

    edge_fused_kernel<<<dim3(BB * LL), dim3(256), 0, stream>>>(pos, frag, emb, out);
}